// Round 13
// baseline (238.962 us; speedup 1.0000x reference)
//
#include <hip/hip_runtime.h>
#include <cstddef>

// Problem constants (match reference)
constexpr int Bn   = 2048;
constexpr int Dn   = 512;
constexpr int NCLS = 100;
constexpr int CAP  = 131072;      // window key capacity (expect ~41K)
constexpr unsigned WWIN = 32768;  // window width in key units (ulp = 2^-20 at |L|~14.3)

// VERIFIED INVARIANT (R4): reference adc[i][j] = fl32( single fma chain k=0..511 ) / 0.07f,
// strict ascending k, one fused fma per step, single fp32 accumulator. DO NOT reassociate,
// split K, or use MFMA — masks flip at sub-ulp rank gaps.
// adc bitwise symmetric -> lower triangle + mirror. Row max == diag == fl32(chain(F[i]·F[i]))/0.07f.
// STABILITY (R9-R11 bisect): 528-block/256-thread gemm structure is HW-proven; single-wave
// 2080-block variant killed containers twice. Do not revisit. Mask planes start at out+1
// (4-mod-16 addresses): use __builtin_memcpy for 16B stores, never assert 16B alignment.

struct Ctl {
  unsigned above;      // 0:  # negatives with key >= window hi
  unsigned candCount;  // 4:  # keys collected in window
  unsigned singles;    // 8
  unsigned done;       // 12: final_k completion counter
  float    thrF;       // 16
  unsigned pad1;       // 20
  double   lossSum;    // 24..31
  unsigned hist[4096]; // 32; window histogram, 8-ulp bins (built in gemm epilogue)
  unsigned cand[CAP];  // 16416; 16-byte aligned
};
static_assert(offsetof(Ctl, cand) % 16 == 0, "cand must be 16B aligned");

// Monotone fp32 <-> uint32 order keys
__device__ inline unsigned key_of(float L) {
  unsigned u = __float_as_uint(L);
  return (u & 0x80000000u) ? ~u : (u | 0x80000000u);
}
__device__ inline float key_to_float(unsigned key) {
  unsigned u = (key & 0x80000000u) ? (key ^ 0x80000000u) : ~key;
  return __uint_as_float(u);
}
// Window: centered at -1/0.07 (negative-pair median), +-16384 ulps (~28 sigma of median est.)
__device__ inline unsigned wlo_key() {
  const float c0 = -1.0f / 0.07f;
  return key_of(c0) - (WWIN / 2);
}
// 16B store to a 4B-aligned address (compiler emits legal dword-aligned dwordx4 or splits)
__device__ inline void store16_a4(float* p, float4 v) {
  __builtin_memcpy((void*)p, &v, 16);
}

// ---------------- per-row self-dot: rm[i] bitwise == adc[i][i] ----------------
__global__ __launch_bounds__(256) void rowdot_k(const float* __restrict__ F,
                                                float* __restrict__ rm) {
  const int i = blockIdx.x * 256 + threadIdx.x;
  const float4* p = (const float4*)(F + (size_t)i * Dn);
  float acc = 0.0f;
#pragma unroll 16
  for (int q = 0; q < 128; ++q) {
    const float4 f = p[q];
    acc = __builtin_fmaf(f.x, f.x, acc);
    acc = __builtin_fmaf(f.y, f.y, acc);
    acc = __builtin_fmaf(f.z, f.z, acc);
    acc = __builtin_fmaf(f.w, f.w, acc);   // strict ascending-k chain, same as gemm
  }
  rm[i] = acc / 0.07f;                     // IEEE fp32 div: bitwise == adc[i][i]
}

// -------- GEMM: lower-triangle 64x64 tiles + mirror + fused window stats (R12-proven) --------
__global__ __launch_bounds__(256) void gemm_adc(const float* __restrict__ F,
                                                const float* __restrict__ rm,
                                                const int* __restrict__ labels,
                                                float* __restrict__ adc, Ctl* c) {
  __shared__ float smem[4352];   // As dbuf [0,2176), Bs dbuf [2176,4352); reused as 64x68 transpose
  __shared__ int slabi[64], slabj[64];
  __shared__ float rmiA[64], rmjA[64];
  __shared__ unsigned wlist[1024];
  __shared__ unsigned wcnt, abcnt, gbase;
  const int t = threadIdx.x;
  int r = 0;
  { const int idx = blockIdx.x; while ((r + 1) * (r + 2) / 2 <= idx) ++r; }
  const int cc = blockIdx.x - r * (r + 1) / 2;
  const int i0 = r * 64, j0 = cc * 64;

  const int tx = t & 15, ty = t >> 4;        // 16x16 thread grid, 4x4 microtile
  const int lrow = t >> 2, lq = t & 3;       // loader: row 0..63, k-quad 0..3

  if (t < 64) {
    slabi[t] = labels[i0 + t]; rmiA[t] = rm[i0 + t];
    slabj[t] = labels[j0 + t]; rmjA[t] = rm[j0 + t];
  }
  if (t == 0) { wcnt = 0; abcnt = 0; gbase = 0; }

  float acc[4][4] = {};
  const float* Ab = F + (size_t)(i0 + lrow) * Dn;
  const float* Bb = F + (size_t)(j0 + lrow) * Dn;
  float* As = smem;          // [buf*1088 + k*68 + row]
  float* Bs = smem + 2176;

  float4 a = *(const float4*)(Ab + lq * 4);
  float4 b = *(const float4*)(Bb + lq * 4);
  {
    const int k0 = lq * 4;
    As[(k0 + 0) * 68 + lrow] = a.x; As[(k0 + 1) * 68 + lrow] = a.y;
    As[(k0 + 2) * 68 + lrow] = a.z; As[(k0 + 3) * 68 + lrow] = a.w;
    Bs[(k0 + 0) * 68 + lrow] = b.x; Bs[(k0 + 1) * 68 + lrow] = b.y;
    Bs[(k0 + 2) * 68 + lrow] = b.z; Bs[(k0 + 3) * 68 + lrow] = b.w;
  }
  __syncthreads();

  for (int ch = 0; ch < 32; ++ch) {
    const int cur = ch & 1, nxt = cur ^ 1;
    if (ch < 31) {
      const int kg = (ch + 1) * 16;
      a = *(const float4*)(Ab + kg + lq * 4);
      b = *(const float4*)(Bb + kg + lq * 4);
    }
    const float* Ac = As + cur * 1088;
    const float* Bc = Bs + cur * 1088;
#pragma unroll
    for (int k = 0; k < 16; ++k) {
      const float4 av = *(const float4*)(Ac + k * 68 + ty * 4);
      const float4 bv = *(const float4*)(Bc + k * 68 + tx * 4);
      const float aa[4] = {av.x, av.y, av.z, av.w};
      const float bb[4] = {bv.x, bv.y, bv.z, bv.w};
#pragma unroll
      for (int m = 0; m < 4; ++m)
#pragma unroll
        for (int n = 0; n < 4; ++n)
          acc[m][n] = __builtin_fmaf(aa[m], bb[n], acc[m][n]);  // strict k-order chain
    }
    if (ch < 31) {
      const int k0 = lq * 4;
      float* An = As + nxt * 1088;
      float* Bm = Bs + nxt * 1088;
      An[(k0 + 0) * 68 + lrow] = a.x; An[(k0 + 1) * 68 + lrow] = a.y;
      An[(k0 + 2) * 68 + lrow] = a.z; An[(k0 + 3) * 68 + lrow] = a.w;
      Bm[(k0 + 0) * 68 + lrow] = b.x; Bm[(k0 + 1) * 68 + lrow] = b.y;
      Bm[(k0 + 2) * 68 + lrow] = b.z; Bm[(k0 + 3) * 68 + lrow] = b.w;
    }
    __syncthreads();
  }

  // epilogue: /0.07f, store own tile
  float v[4][4];
#pragma unroll
  for (int m = 0; m < 4; ++m) {
#pragma unroll
    for (int n = 0; n < 4; ++n) v[m][n] = acc[m][n] / 0.07f;   // IEEE fp32 div
    float4 q = {v[m][0], v[m][1], v[m][2], v[m][3]};
    *(float4*)&adc[(size_t)(i0 + ty * 4 + m) * Bn + j0 + tx * 4] = q;
  }
  if (r != cc) {
    // mirror via LDS transpose (bitwise-identical values)
    __syncthreads();               // block-uniform; k-loop LDS reads done
    float* T = smem;               // 64 x 68
#pragma unroll
    for (int m = 0; m < 4; ++m)
#pragma unroll
      for (int n = 0; n < 4; ++n)
        T[(tx * 4 + n) * 68 + (ty * 4 + m)] = v[m][n];
    __syncthreads();
#pragma unroll
    for (int e = 0; e < 4; ++e) {
      const int row2 = e * 16 + ty;  // mirror row = original col
      *(float4*)&adc[(size_t)(j0 + row2) * Bn + i0 + tx * 4] =
          *(const float4*)(T + row2 * 68 + tx * 4);
    }
  }

  // fused window statistics (own tile + mirror), values still in registers
  __syncthreads();
  const unsigned klo = wlo_key(), khi = klo + WWIN;
  unsigned myab = 0;
#pragma unroll
  for (int m = 0; m < 4; ++m) {
    const int gi = i0 + ty * 4 + m;
    const int li = slabi[ty * 4 + m];
    const float rmi = rmiA[ty * 4 + m];
#pragma unroll
    for (int n = 0; n < 4; ++n) {
      const int gj = j0 + tx * 4 + n;
      if (gi == gj || li == slabj[tx * 4 + n]) continue;
      const unsigned key = key_of(v[m][n] - rmi);   // exact fp32 sub
      if (key >= khi) ++myab;
      else if (key >= klo) {
        atomicAdd(&c->hist[(key - klo) >> 3], 1u);
        const unsigned p = atomicAdd(&wcnt, 1u);
        if (p < 1024u) wlist[p] = key;
      }
      if (r != cc) {
        const unsigned key2 = key_of(v[m][n] - rmjA[tx * 4 + n]);
        if (key2 >= khi) ++myab;
        else if (key2 >= klo) {
          atomicAdd(&c->hist[(key2 - klo) >> 3], 1u);
          const unsigned p = atomicAdd(&wcnt, 1u);
          if (p < 1024u) wlist[p] = key2;
        }
      }
    }
  }
  if (myab) atomicAdd(&abcnt, myab);
  __syncthreads();
  if (t == 0) {
    if (abcnt) atomicAdd(&c->above, abcnt);
    const unsigned nl = wcnt < 1024u ? wcnt : 1024u;
    gbase = nl ? atomicAdd(&c->candCount, nl) : 0u;
  }
  __syncthreads();
  const unsigned nl = wcnt < 1024u ? wcnt : 1024u;
  for (unsigned q = t; q < nl; q += 256) {
    const unsigned p = gbase + q;
    if (p < (unsigned)CAP) c->cand[p] = wlist[q];
  }
}

// ------------- single-block select: fused classcnt->k, hist->bucket, vector cand scan -------------
__global__ __launch_bounds__(256) void select_k(const int* __restrict__ labels, Ctl* c) {
  __shared__ unsigned cnt[NCLS];
  __shared__ unsigned tsum[256], suffix[256];
  __shared__ unsigned skk;
  __shared__ int sbd;
  __shared__ unsigned sab, m;
  __shared__ unsigned list[256];
  const int t = threadIdx.x;
  if (t < NCLS) cnt[t] = 0;
  if (t == 0) { m = 0; sbd = 0; sab = 0; }
  __syncthreads();
  for (int j = t; j < Bn; j += 256) atomicAdd(&cnt[labels[j]], 1u);
  __syncthreads();
  if (t == 0) {
    unsigned s = 0;
    for (int h = 0; h < NCLS; ++h) s += cnt[h] * cnt[h];
    unsigned nneg = (unsigned)Bn * Bn - s;
    unsigned k = nneg >> 1;                  // floor(0.5*n_neg), exact vs ref
    if (k < 1) k = 1;
    skk = k;
  }
  const uint4* hp = (const uint4*)c->hist;
  uint4 h0 = hp[t * 4 + 0], h1 = hp[t * 4 + 1], h2 = hp[t * 4 + 2], h3 = hp[t * 4 + 3];
  const unsigned hv[16] = {h0.x, h0.y, h0.z, h0.w, h1.x, h1.y, h1.z, h1.w,
                           h2.x, h2.y, h2.z, h2.w, h3.x, h3.y, h3.z, h3.w};
  unsigned s = 0;
#pragma unroll
  for (int u = 0; u < 16; ++u) s += hv[u];
  tsum[t] = s;
  __syncthreads();
  if (t == 0) {
    unsigned acc = c->above;
    for (int q = 255; q >= 0; --q) { suffix[q] = acc; acc += tsum[q]; }
  }
  __syncthreads();
  const unsigned kk = skk;
  unsigned cum = suffix[t];
#pragma unroll
  for (int u = 15; u >= 0; --u) {
    if (cum < kk && cum + hv[u] >= kk) { sbd = t * 16 + u; sab = cum; }
    cum += hv[u];
  }
  __syncthreads();
  const int bd = sbd;
  const unsigned rr = kk - sab;   // 1-indexed rank within bucket
  const unsigned klo = wlo_key();
  unsigned n = c->candCount; if (n > (unsigned)CAP) n = (unsigned)CAP;
  const unsigned n4 = n >> 2;
  const uint4* cp = (const uint4*)c->cand;
  unsigned q = t;
  for (; q + 7u * 256u < n4; q += 8u * 256u) {   // 8 independent 16B loads in flight
    uint4 v[8];
#pragma unroll
    for (int u = 0; u < 8; ++u) v[u] = cp[q + (unsigned)u * 256u];
#pragma unroll
    for (int u = 0; u < 8; ++u) {
      const unsigned ks[4] = {v[u].x, v[u].y, v[u].z, v[u].w};
#pragma unroll
      for (int w = 0; w < 4; ++w) {
        const unsigned d = ks[w] - klo;
        if (d < WWIN && (int)(d >> 3) == bd) {
          const unsigned p = atomicAdd(&m, 1u);
          if (p < 256u) list[p] = ks[w];
        }
      }
    }
  }
  for (; q < n4; q += 256u) {
    const uint4 v = cp[q];
    const unsigned ks[4] = {v.x, v.y, v.z, v.w};
#pragma unroll
    for (int w = 0; w < 4; ++w) {
      const unsigned d = ks[w] - klo;
      if (d < WWIN && (int)(d >> 3) == bd) {
        const unsigned p = atomicAdd(&m, 1u);
        if (p < 256u) list[p] = ks[w];
      }
    }
  }
  for (unsigned e = n4 * 4u + t; e < n; e += 256u) {
    const unsigned key = c->cand[e];
    const unsigned d = key - klo;
    if (d < WWIN && (int)(d >> 3) == bd) {
      const unsigned p = atomicAdd(&m, 1u);
      if (p < 256u) list[p] = key;
    }
  }
  __syncthreads();
  const unsigned mm = m > 256u ? 256u : m;
  for (unsigned e = t; e < mm; e += 256) {
    const unsigned v = list[e];
    unsigned g = 0, ge = 0;
    for (unsigned j = 0; j < mm; ++j) {
      g  += (list[j] > v);
      ge += (list[j] >= v);
    }
    if (g < rr && rr <= ge) c->thrF = key_to_float(v);  // duplicates write same value
  }
}

__device__ inline float block_sum_f(float v) {
  __shared__ float s[4];
#pragma unroll
  for (int o = 32; o > 0; o >>= 1) v += __shfl_down(v, o, 64);
  const int lane = threadIdx.x & 63, w = threadIdx.x >> 6;
  __syncthreads();
  if (lane == 0) s[w] = v;
  __syncthreads();
  return s[0] + s[1] + s[2] + s[3];
}

// ------- fused mask + loss: float4 loads, 16B mask stores, last-block finalize -------
__global__ __launch_bounds__(256) void final_k(const float* __restrict__ adc,
                                               const int* __restrict__ labels,
                                               Ctl* c, float* __restrict__ out) {
  __shared__ int slab[Bn];
  const int i = blockIdx.x;
  const int t = threadIdx.x;
#pragma unroll
  for (int e = 0; e < 2; ++e)                      // int4 slab staging
    ((int4*)slab)[t + 256 * e] = ((const int4*)labels)[t + 256 * e];
  __syncthreads();
  const int li = slab[i];
  const float rm = adc[(size_t)i * Bn + i];        // diag == row max (bitwise)
  const float thr = c->thrF;
  float* __restrict__ ohnm = out + 1;
  float* __restrict__ ofin = out + 1 + (size_t)Bn * Bn;
  const float4* rowp = (const float4*)(adc + (size_t)i * Bn);

  float se = 0.0f, sp = 0.0f;
  int pcnt = 0;
#pragma unroll
  for (int e = 0; e < 2; ++e) {
    const int jq = t + 256 * e;
    const float4 vv = rowp[jq];
    const int jb = jq * 4;
    const float vs[4] = {vv.x, vv.y, vv.z, vv.w};
    float qh[4], qf[4];
#pragma unroll
    for (int u = 0; u < 4; ++u) {
      const int j = jb + u;
      const float L = vs[u] - rm;                  // identical fp32 value as gemm epilogue
      const bool offd = (j != i);
      const bool same = (slab[j] == li);
      const bool hnm  = offd && !same && (L >= thr);
      const bool fin  = offd && (same || hnm);
      if (offd) se += __expf(L);
      if (fin)  { sp += L; ++pcnt; }
      qh[u] = hnm ? 1.0f : 0.0f;
      qf[u] = fin ? 1.0f : 0.0f;
    }
    float4 h4 = {qh[0], qh[1], qh[2], qh[3]};
    float4 f4 = {qf[0], qf[1], qf[2], qf[3]};
    store16_a4(&ohnm[(size_t)i * Bn + jb], h4);    // 4-mod-16 address: memcpy path
    store16_a4(&ofin[(size_t)i * Bn + jb], f4);
  }
  se = block_sum_f(se);
  sp = block_sum_f(sp);
  float pcf = block_sum_f((float)pcnt);
  if (t == 0) {
    const double P = (double)pcf;
    const bool single = (P == 0.0);
    const double mlpp = ((double)sp - P * log((double)se + 1e-12)) / (P + (single ? 1.0 : 0.0));
    const double lv = single ? 0.0 : -mlpp;
    atomicAdd(&c->lossSum, lv);
    if (single) atomicAdd(&c->singles, 1u);
    __threadfence();                               // device-scope: publish before ticket
    const unsigned ticket = atomicAdd(&c->done, 1u);
    if (ticket == (unsigned)Bn - 1u) {             // last block: all adds are visible
      const double ls = atomicAdd(&c->lossSum, 0.0);
      const unsigned sg = atomicAdd(&c->singles, 0u);
      out[0] = (float)(ls / ((double)Bn - (double)sg));
    }
  }
}

// ---------------- launch ----------------
extern "C" void kernel_launch(void* const* d_in, const int* in_sizes, int n_in,
                              void* d_out, int out_size, void* d_ws, size_t ws_size,
                              hipStream_t stream) {
  const float* F      = (const float*)d_in[0];
  const int*   labels = (const int*)d_in[1];
  float* out = (float*)d_out;

  char* ws = (char*)d_ws;
  Ctl*   c   = (Ctl*)ws;                                    // ~541 KB
  float* rm  = (float*)(ws + 786432);                       // 768 KB offset, 8 KB
  float* adc = (float*)(ws + (1u << 20));                   // 1 MiB offset, 16.78 MB

  hipMemsetAsync(c, 0, offsetof(Ctl, cand), stream);        // head (incl. done) + hist

  rowdot_k<<<Bn / 256, 256, 0, stream>>>(F, rm);
  gemm_adc<<<528, 256, 0, stream>>>(F, rm, labels, adc, c); // triangle tiles + fused window
  select_k<<<1, 256, 0, stream>>>(labels, c);
  final_k<<<Bn, 256, 0, stream>>>(adc, labels, c, out);     // + last-block finalize
}

// Round 14
// 181.338 us; speedup vs baseline: 1.3178x; 1.3178x over previous
//
#include <hip/hip_runtime.h>
#include <cstddef>

// Problem constants (match reference)
constexpr int Bn   = 2048;
constexpr int Dn   = 512;
constexpr int NCLS = 100;
constexpr int CAP  = 131072;      // window key capacity (expect ~41K)
constexpr unsigned WWIN = 32768;  // window width in key units (ulp = 2^-20 at |L|~14.3)

// VERIFIED INVARIANT (R4): reference adc[i][j] = fl32( single fma chain k=0..511 ) / 0.07f,
// strict ascending k, one fused fma per step, single fp32 accumulator. DO NOT reassociate,
// split K, or use MFMA — masks flip at sub-ulp rank gaps.
// adc bitwise symmetric -> lower triangle + mirror. Row max == diag == fl32(chain(F[i]·F[i]))/0.07f.
// STABILITY (R9-R11 bisect): 528-block/256-thread gemm structure is HW-proven; single-wave
// 2080-block variant killed containers twice. Do not revisit. Mask planes start at out+1
// (4-mod-16 addresses): 16B stores only via __builtin_memcpy; never cast to float4*.
// Cross-XCD: all inter-block communication through device-scope atomics (proven R13).

struct Ctl {
  unsigned above;      // 0:  # negatives with key >= window hi
  unsigned candCount;  // 4:  # keys collected in window
  unsigned singles;    // 8
  unsigned done;       // 12: final_k completion counter
  float    thrF;       // 16
  unsigned pad1;       // 20
  double   lossSum;    // 24..31
  unsigned hist[4096]; // 32; window histogram, 8-ulp bins (built in gemm epilogue)
  unsigned cand[CAP];  // 16416; 16-byte aligned
};
static_assert(offsetof(Ctl, cand) % 16 == 0, "cand must be 16B aligned");

// Monotone fp32 <-> uint32 order keys
__device__ inline unsigned key_of(float L) {
  unsigned u = __float_as_uint(L);
  return (u & 0x80000000u) ? ~u : (u | 0x80000000u);
}
__device__ inline float key_to_float(unsigned key) {
  unsigned u = (key & 0x80000000u) ? (key ^ 0x80000000u) : ~key;
  return __uint_as_float(u);
}
// Window: centered at -1/0.07 (negative-pair median), +-16384 ulps (~28 sigma of median est.)
__device__ inline unsigned wlo_key() {
  const float c0 = -1.0f / 0.07f;
  return key_of(c0) - (WWIN / 2);
}
// 16B store to a 4B-aligned address (compiler emits legal dword stores)
__device__ inline void store16_a4(float* p, float4 v) {
  __builtin_memcpy((void*)p, &v, 16);
}

// ---------------- per-row self-dot: rm[i] bitwise == adc[i][i] ----------------
__global__ __launch_bounds__(256) void rowdot_k(const float* __restrict__ F,
                                                float* __restrict__ rm) {
  const int i = blockIdx.x * 256 + threadIdx.x;
  const float4* p = (const float4*)(F + (size_t)i * Dn);
  float acc = 0.0f;
#pragma unroll 16
  for (int q = 0; q < 128; ++q) {
    const float4 f = p[q];
    acc = __builtin_fmaf(f.x, f.x, acc);
    acc = __builtin_fmaf(f.y, f.y, acc);
    acc = __builtin_fmaf(f.z, f.z, acc);
    acc = __builtin_fmaf(f.w, f.w, acc);   // strict ascending-k chain, same as gemm
  }
  rm[i] = acc / 0.07f;                     // IEEE fp32 div: bitwise == adc[i][i]
}

// -------- GEMM: lower-triangle 64x64 tiles + mirror + fused window stats (R12-proven) --------
__global__ __launch_bounds__(256) void gemm_adc(const float* __restrict__ F,
                                                const float* __restrict__ rm,
                                                const int* __restrict__ labels,
                                                float* __restrict__ adc, Ctl* c) {
  __shared__ float smem[4352];   // As dbuf [0,2176), Bs dbuf [2176,4352); reused as 64x68 transpose
  __shared__ int slabi[64], slabj[64];
  __shared__ float rmiA[64], rmjA[64];
  __shared__ unsigned wlist[1024];
  __shared__ unsigned wcnt, abcnt, gbase;
  const int t = threadIdx.x;
  int r = 0;
  { const int idx = blockIdx.x; while ((r + 1) * (r + 2) / 2 <= idx) ++r; }
  const int cc = blockIdx.x - r * (r + 1) / 2;
  const int i0 = r * 64, j0 = cc * 64;

  const int tx = t & 15, ty = t >> 4;        // 16x16 thread grid, 4x4 microtile
  const int lrow = t >> 2, lq = t & 3;       // loader: row 0..63, k-quad 0..3

  if (t < 64) {
    slabi[t] = labels[i0 + t]; rmiA[t] = rm[i0 + t];
    slabj[t] = labels[j0 + t]; rmjA[t] = rm[j0 + t];
  }
  if (t == 0) { wcnt = 0; abcnt = 0; gbase = 0; }

  float acc[4][4] = {};
  const float* Ab = F + (size_t)(i0 + lrow) * Dn;
  const float* Bb = F + (size_t)(j0 + lrow) * Dn;
  float* As = smem;          // [buf*1088 + k*68 + row]
  float* Bs = smem + 2176;

  float4 a = *(const float4*)(Ab + lq * 4);
  float4 b = *(const float4*)(Bb + lq * 4);
  {
    const int k0 = lq * 4;
    As[(k0 + 0) * 68 + lrow] = a.x; As[(k0 + 1) * 68 + lrow] = a.y;
    As[(k0 + 2) * 68 + lrow] = a.z; As[(k0 + 3) * 68 + lrow] = a.w;
    Bs[(k0 + 0) * 68 + lrow] = b.x; Bs[(k0 + 1) * 68 + lrow] = b.y;
    Bs[(k0 + 2) * 68 + lrow] = b.z; Bs[(k0 + 3) * 68 + lrow] = b.w;
  }
  __syncthreads();

  for (int ch = 0; ch < 32; ++ch) {
    const int cur = ch & 1, nxt = cur ^ 1;
    if (ch < 31) {
      const int kg = (ch + 1) * 16;
      a = *(const float4*)(Ab + kg + lq * 4);
      b = *(const float4*)(Bb + kg + lq * 4);
    }
    const float* Ac = As + cur * 1088;
    const float* Bc = Bs + cur * 1088;
#pragma unroll
    for (int k = 0; k < 16; ++k) {
      const float4 av = *(const float4*)(Ac + k * 68 + ty * 4);
      const float4 bv = *(const float4*)(Bc + k * 68 + tx * 4);
      const float aa[4] = {av.x, av.y, av.z, av.w};
      const float bb[4] = {bv.x, bv.y, bv.z, bv.w};
#pragma unroll
      for (int m = 0; m < 4; ++m)
#pragma unroll
        for (int n = 0; n < 4; ++n)
          acc[m][n] = __builtin_fmaf(aa[m], bb[n], acc[m][n]);  // strict k-order chain
    }
    if (ch < 31) {
      const int k0 = lq * 4;
      float* An = As + nxt * 1088;
      float* Bm = Bs + nxt * 1088;
      An[(k0 + 0) * 68 + lrow] = a.x; An[(k0 + 1) * 68 + lrow] = a.y;
      An[(k0 + 2) * 68 + lrow] = a.z; An[(k0 + 3) * 68 + lrow] = a.w;
      Bm[(k0 + 0) * 68 + lrow] = b.x; Bm[(k0 + 1) * 68 + lrow] = b.y;
      Bm[(k0 + 2) * 68 + lrow] = b.z; Bm[(k0 + 3) * 68 + lrow] = b.w;
    }
    __syncthreads();
  }

  // epilogue: /0.07f, store own tile
  float v[4][4];
#pragma unroll
  for (int m = 0; m < 4; ++m) {
#pragma unroll
    for (int n = 0; n < 4; ++n) v[m][n] = acc[m][n] / 0.07f;   // IEEE fp32 div
    float4 q = {v[m][0], v[m][1], v[m][2], v[m][3]};
    *(float4*)&adc[(size_t)(i0 + ty * 4 + m) * Bn + j0 + tx * 4] = q;
  }
  if (r != cc) {
    // mirror via LDS transpose (bitwise-identical values)
    __syncthreads();               // block-uniform; k-loop LDS reads done
    float* T = smem;               // 64 x 68
#pragma unroll
    for (int m = 0; m < 4; ++m)
#pragma unroll
      for (int n = 0; n < 4; ++n)
        T[(tx * 4 + n) * 68 + (ty * 4 + m)] = v[m][n];
    __syncthreads();
#pragma unroll
    for (int e = 0; e < 4; ++e) {
      const int row2 = e * 16 + ty;  // mirror row = original col
      *(float4*)&adc[(size_t)(j0 + row2) * Bn + i0 + tx * 4] =
          *(const float4*)(T + row2 * 68 + tx * 4);
    }
  }

  // fused window statistics (own tile + mirror), values still in registers
  __syncthreads();
  const unsigned klo = wlo_key(), khi = klo + WWIN;
  unsigned myab = 0;
#pragma unroll
  for (int m = 0; m < 4; ++m) {
    const int gi = i0 + ty * 4 + m;
    const int li = slabi[ty * 4 + m];
    const float rmi = rmiA[ty * 4 + m];
#pragma unroll
    for (int n = 0; n < 4; ++n) {
      const int gj = j0 + tx * 4 + n;
      if (gi == gj || li == slabj[tx * 4 + n]) continue;
      const unsigned key = key_of(v[m][n] - rmi);   // exact fp32 sub
      if (key >= khi) ++myab;
      else if (key >= klo) {
        atomicAdd(&c->hist[(key - klo) >> 3], 1u);
        const unsigned p = atomicAdd(&wcnt, 1u);
        if (p < 1024u) wlist[p] = key;
      }
      if (r != cc) {
        const unsigned key2 = key_of(v[m][n] - rmjA[tx * 4 + n]);
        if (key2 >= khi) ++myab;
        else if (key2 >= klo) {
          atomicAdd(&c->hist[(key2 - klo) >> 3], 1u);
          const unsigned p = atomicAdd(&wcnt, 1u);
          if (p < 1024u) wlist[p] = key2;
        }
      }
    }
  }
  if (myab) atomicAdd(&abcnt, myab);
  __syncthreads();
  if (t == 0) {
    if (abcnt) atomicAdd(&c->above, abcnt);
    const unsigned nl = wcnt < 1024u ? wcnt : 1024u;
    gbase = nl ? atomicAdd(&c->candCount, nl) : 0u;
  }
  __syncthreads();
  const unsigned nl = wcnt < 1024u ? wcnt : 1024u;
  for (unsigned q = t; q < nl; q += 256) {
    const unsigned p = gbase + q;
    if (p < (unsigned)CAP) c->cand[p] = wlist[q];
  }
}

// ------------- single-block select: fused classcnt->k, hist->bucket, vector cand scan -------------
__global__ __launch_bounds__(256) void select_k(const int* __restrict__ labels, Ctl* c) {
  __shared__ unsigned cnt[NCLS];
  __shared__ unsigned tsum[256], suffix[256];
  __shared__ unsigned skk;
  __shared__ int sbd;
  __shared__ unsigned sab, m;
  __shared__ unsigned list[256];
  const int t = threadIdx.x;
  if (t < NCLS) cnt[t] = 0;
  if (t == 0) { m = 0; sbd = 0; sab = 0; }
  __syncthreads();
  for (int j = t; j < Bn; j += 256) atomicAdd(&cnt[labels[j]], 1u);
  __syncthreads();
  if (t == 0) {
    unsigned s = 0;
    for (int h = 0; h < NCLS; ++h) s += cnt[h] * cnt[h];
    unsigned nneg = (unsigned)Bn * Bn - s;
    unsigned k = nneg >> 1;                  // floor(0.5*n_neg), exact vs ref
    if (k < 1) k = 1;
    skk = k;
  }
  const uint4* hp = (const uint4*)c->hist;
  uint4 h0 = hp[t * 4 + 0], h1 = hp[t * 4 + 1], h2 = hp[t * 4 + 2], h3 = hp[t * 4 + 3];
  const unsigned hv[16] = {h0.x, h0.y, h0.z, h0.w, h1.x, h1.y, h1.z, h1.w,
                           h2.x, h2.y, h2.z, h2.w, h3.x, h3.y, h3.z, h3.w};
  unsigned s = 0;
#pragma unroll
  for (int u = 0; u < 16; ++u) s += hv[u];
  tsum[t] = s;
  __syncthreads();
  if (t == 0) {
    unsigned acc = c->above;
    for (int q = 255; q >= 0; --q) { suffix[q] = acc; acc += tsum[q]; }
  }
  __syncthreads();
  const unsigned kk = skk;
  unsigned cum = suffix[t];
#pragma unroll
  for (int u = 15; u >= 0; --u) {
    if (cum < kk && cum + hv[u] >= kk) { sbd = t * 16 + u; sab = cum; }
    cum += hv[u];
  }
  __syncthreads();
  const int bd = sbd;
  const unsigned rr = kk - sab;   // 1-indexed rank within bucket
  const unsigned klo = wlo_key();
  unsigned n = c->candCount; if (n > (unsigned)CAP) n = (unsigned)CAP;
  const unsigned n4 = n >> 2;
  const uint4* cp = (const uint4*)c->cand;
  unsigned q = t;
  for (; q + 7u * 256u < n4; q += 8u * 256u) {   // 8 independent 16B loads in flight
    uint4 v[8];
#pragma unroll
    for (int u = 0; u < 8; ++u) v[u] = cp[q + (unsigned)u * 256u];
#pragma unroll
    for (int u = 0; u < 8; ++u) {
      const unsigned ks[4] = {v[u].x, v[u].y, v[u].z, v[u].w};
#pragma unroll
      for (int w = 0; w < 4; ++w) {
        const unsigned d = ks[w] - klo;
        if (d < WWIN && (int)(d >> 3) == bd) {
          const unsigned p = atomicAdd(&m, 1u);
          if (p < 256u) list[p] = ks[w];
        }
      }
    }
  }
  for (; q < n4; q += 256u) {
    const uint4 v = cp[q];
    const unsigned ks[4] = {v.x, v.y, v.z, v.w};
#pragma unroll
    for (int w = 0; w < 4; ++w) {
      const unsigned d = ks[w] - klo;
      if (d < WWIN && (int)(d >> 3) == bd) {
        const unsigned p = atomicAdd(&m, 1u);
        if (p < 256u) list[p] = ks[w];
      }
    }
  }
  for (unsigned e = n4 * 4u + t; e < n; e += 256u) {
    const unsigned key = c->cand[e];
    const unsigned d = key - klo;
    if (d < WWIN && (int)(d >> 3) == bd) {
      const unsigned p = atomicAdd(&m, 1u);
      if (p < 256u) list[p] = key;
    }
  }
  __syncthreads();
  const unsigned mm = m > 256u ? 256u : m;
  for (unsigned e = t; e < mm; e += 256) {
    const unsigned v = list[e];
    unsigned g = 0, ge = 0;
    for (unsigned j = 0; j < mm; ++j) {
      g  += (list[j] > v);
      ge += (list[j] >= v);
    }
    if (g < rr && rr <= ge) c->thrF = key_to_float(v);  // duplicates write same value
  }
}

// ------- fused mask + loss: 256 blocks x 8 rows, one wave per row, block-batched atomics -------
__global__ __launch_bounds__(256) void final_k(const float* __restrict__ adc,
                                               const int* __restrict__ labels,
                                               Ctl* c, float* __restrict__ out) {
  __shared__ int slab[Bn];
  __shared__ double lsum[8];
  __shared__ unsigned sflag[8];
  const int t = threadIdx.x;
  const int lane = t & 63, w = t >> 6;
#pragma unroll
  for (int e = 0; e < 2; ++e)                      // int4 slab staging, once per 8 rows
    ((int4*)slab)[t + 256 * e] = ((const int4*)labels)[t + 256 * e];
  __syncthreads();
  const float thr = c->thrF;
  float* __restrict__ ohnm = out + 1;
  float* __restrict__ ofin = out + 1 + (size_t)Bn * Bn;

#pragma unroll
  for (int rr = 0; rr < 2; ++rr) {                 // wave w owns rows b*8 + rr*4 + w
    const int i = blockIdx.x * 8 + rr * 4 + w;
    const int li = slab[i];
    const float rm = adc[(size_t)i * Bn + i];      // diag == row max (bitwise)
    const float4* rowp = (const float4*)(adc + (size_t)i * Bn);
    float se = 0.0f, sp = 0.0f;
    int pc = 0;
#pragma unroll
    for (int q = 0; q < 8; ++q) {
      const int j4 = lane + 64 * q;                // wave instr covers 1KB contiguous
      const float4 vv = rowp[j4];
      const int jb = j4 * 4;
      const float vs[4] = {vv.x, vv.y, vv.z, vv.w};
      float qh[4], qf[4];
#pragma unroll
      for (int u = 0; u < 4; ++u) {
        const int j = jb + u;
        const float L = vs[u] - rm;                // identical fp32 value as gemm epilogue
        const bool offd = (j != i);
        const bool same = (slab[j] == li);
        const bool hnm  = offd && !same && (L >= thr);
        const bool fin  = offd && (same || hnm);
        if (offd) se += __expf(L);
        if (fin)  { sp += L; ++pc; }
        qh[u] = hnm ? 1.0f : 0.0f;
        qf[u] = fin ? 1.0f : 0.0f;
      }
      float4 h4 = {qh[0], qh[1], qh[2], qh[3]};
      float4 f4 = {qf[0], qf[1], qf[2], qf[3]};
      store16_a4(&ohnm[(size_t)i * Bn + jb], h4);  // 4-mod-16 address: memcpy path
      store16_a4(&ofin[(size_t)i * Bn + jb], f4);
    }
    float pcf = (float)pc;
#pragma unroll
    for (int o = 32; o > 0; o >>= 1) {             // wave-only reduction, no barriers
      se  += __shfl_down(se,  o, 64);
      sp  += __shfl_down(sp,  o, 64);
      pcf += __shfl_down(pcf, o, 64);
    }
    if (lane == 0) {
      const double P = (double)pcf;
      const bool single = (P == 0.0);
      const double mlpp = ((double)sp - P * log((double)se + 1e-12)) / (P + (single ? 1.0 : 0.0));
      lsum[w * 2 + rr]  = single ? 0.0 : -mlpp;
      sflag[w * 2 + rr] = single ? 1u : 0u;
    }
  }
  __syncthreads();
  if (t == 0) {
    double ls = 0.0;
    unsigned sc = 0;
    for (int e = 0; e < 8; ++e) { ls += lsum[e]; sc += sflag[e]; }
    atomicAdd(&c->lossSum, ls);                    // one contended atomic per block (256 total)
    if (sc) atomicAdd(&c->singles, sc);
    __threadfence();
    const unsigned ticket = atomicAdd(&c->done, 1u);
    if (ticket == 255u) {                          // last block: atomic reads (XCD-coherent)
      const double tot = atomicAdd(&c->lossSum, 0.0);
      const unsigned sg = atomicAdd(&c->singles, 0u);
      out[0] = (float)(tot / ((double)Bn - (double)sg));
    }
  }
}

// ---------------- launch ----------------
extern "C" void kernel_launch(void* const* d_in, const int* in_sizes, int n_in,
                              void* d_out, int out_size, void* d_ws, size_t ws_size,
                              hipStream_t stream) {
  const float* F      = (const float*)d_in[0];
  const int*   labels = (const int*)d_in[1];
  float* out = (float*)d_out;

  char* ws = (char*)d_ws;
  Ctl*   c   = (Ctl*)ws;                                    // ~541 KB
  float* rm  = (float*)(ws + 786432);                       // 768 KB offset, 8 KB
  float* adc = (float*)(ws + (1u << 20));                   // 1 MiB offset, 16.78 MB

  hipMemsetAsync(c, 0, offsetof(Ctl, cand), stream);        // head (incl. done) + hist

  rowdot_k<<<Bn / 256, 256, 0, stream>>>(F, rm);
  gemm_adc<<<528, 256, 0, stream>>>(F, rm, labels, adc, c); // triangle tiles + fused window
  select_k<<<1, 256, 0, stream>>>(labels, c);
  final_k<<<256, 256, 0, stream>>>(adc, labels, c, out);    // 8 rows/block + last-block finalize
}